// Round 6
// baseline (1051.901 us; speedup 1.0000x reference)
//
#include <hip/hip_runtime.h>
#include <hip/hip_bf16.h>
#include <math.h>

#define NN 50000
#define NE 800000
#define NG 64
#define NEXP 8

typedef __attribute__((ext_vector_type(8))) short bf16x8;
typedef __attribute__((ext_vector_type(4))) float f32x4;
typedef unsigned short ushort_t;

#define NT1 782      // layer1 tiles: 391 m-tiles x 2 n-tiles
#define NAGG 12500   // agg blocks: 50000 nodes / 4 waves per block
#define MAXT2 (391 + NEXP)

__device__ __forceinline__ unsigned short f2bf(float f) {
  union { float f; unsigned u; } x; x.f = f;
  unsigned r = x.u + 0x7fff + ((x.u >> 16) & 1);  // RNE
  return (unsigned short)(r >> 16);
}
__device__ __forceinline__ float bf2f(unsigned short u) {
  union { unsigned u; float f; } x; x.u = ((unsigned)u) << 16; return x.f;
}

__device__ __forceinline__ void gld16(const void* g, void* l) {
  __builtin_amdgcn_global_load_lds(
      (const __attribute__((address_space(1))) unsigned int*)g,
      (__attribute__((address_space(3))) unsigned int*)l, 16, 0, 0);
}

// -------- encoder: h = relu(x@W_enc+b); fp32 copy for router, bf16 for MFMA --
__global__ __launch_bounds__(256) void k_encoder(
    const float* __restrict__ x, const float* __restrict__ W,
    const float* __restrict__ b, float* __restrict__ H32,
    ushort_t* __restrict__ Xb) {
  int i = blockIdx.x, n = threadIdx.x;
  float acc = b[n];
#pragma unroll
  for (int k = 0; k < 6; k++) acc = fmaf(x[i * 6 + k], W[k * 256 + n], acc);
  acc = fmaxf(acc, 0.f);
  H32[i * 256 + n] = acc;
  Xb[(size_t)i * 512 + n] = f2bf(acc);
}

// ------ merged per-graph node+edge histograms + in-degree (one dispatch) ----
__global__ __launch_bounds__(256) void k_counts(
    const int* __restrict__ batch, const int* __restrict__ ei,
    int* __restrict__ node_cnt, int* __restrict__ edge_cnt,
    int* __restrict__ deg) {
  __shared__ int bn[NG], be[NG];
  int t = threadIdx.x;
  if (t < NG) { bn[t] = 0; be[t] = 0; }
  __syncthreads();
  for (int i = blockIdx.x * 256 + t; i < NN; i += gridDim.x * 256)
    atomicAdd(&bn[batch[i]], 1);
  for (int e = blockIdx.x * 256 + t; e < NE; e += gridDim.x * 256) {
    int s = ei[e];
    int d = ei[NE + e];
    atomicAdd(&be[batch[s]], 1);
    atomicAdd(&deg[d], 1);
  }
  __syncthreads();
  if (t < NG) {
    atomicAdd(&node_cnt[t], bn[t]);
    atomicAdd(&edge_cnt[t], be[t]);
  }
}

// ---------------- exclusive prefix scan of deg (single block) ----------------
__global__ __launch_bounds__(1024) void k_scan(
    const int* __restrict__ deg, int* __restrict__ offs, int* __restrict__ cursor) {
  __shared__ int wsums[16];
  int t = threadIdx.x, lane = t & 63, wid = t >> 6;
  int carry = 0;
  for (int base = 0; base < NN; base += 1024) {
    int i = base + t;
    int v = (i < NN) ? deg[i] : 0;
    int x = v;
#pragma unroll
    for (int d = 1; d < 64; d <<= 1) {
      int y = __shfl_up(x, d, 64);
      if (lane >= d) x += y;
    }
    if (lane == 63) wsums[wid] = x;
    __syncthreads();
    if (wid == 0) {
      int s = (lane < 16) ? wsums[lane] : 0;
#pragma unroll
      for (int d = 1; d < 16; d <<= 1) {
        int y = __shfl_up(s, d, 64);
        if (lane >= d) s += y;
      }
      if (lane < 16) wsums[lane] = s;
    }
    __syncthreads();
    int wpre = (wid > 0) ? wsums[wid - 1] : 0;
    int excl = carry + wpre + x - v;
    if (i < NN) { offs[i] = excl; cursor[i] = excl; }
    int btot = wsums[15];
    __syncthreads();
    carry += btot;
  }
  if (t == 0) offs[NN] = carry;
}

// ---------------- CSR fill: bucket edges by dst ----------------
__global__ __launch_bounds__(256) void k_fill_csr(
    const int* __restrict__ ei, int* __restrict__ cursor, int* __restrict__ edge_src) {
  int e = blockIdx.x * blockDim.x + threadIdx.x;
  if (e < NE) {
    int d = ei[NE + e];
    int pos = atomicAdd(&cursor[d], 1);
    edge_src[pos] = ei[e];
  }
}

// ---- fused: blocks [0,NAGG) agg_h; blocks [NAGG, NAGG+2048) prep_w ---------
__global__ __launch_bounds__(256) void k_aggh_prepw(
    const int* __restrict__ offs, const int* __restrict__ edge_src,
    ushort_t* __restrict__ Xb,
    const float* __restrict__ Ws0, const float* __restrict__ Wn0,
    const float* __restrict__ Ws1, const float* __restrict__ Wn1,
    ushort_t* __restrict__ Wt1, ushort_t* __restrict__ Wt2) {
  __shared__ float tile[32][33];
  int t = threadIdx.x;
  if ((int)blockIdx.x < NAGG) {
    // agg_h: A_h[i] = sum h_bf[j], into Xb[:, 256:512]
    int wid = t >> 6, lane = t & 63;
    int i = blockIdx.x * 4 + wid;
    if (i >= NN) return;
    int e0 = offs[i], e1 = offs[i + 1];
    float acc[4] = {0.f, 0.f, 0.f, 0.f};
    for (int e = e0; e < e1; e++) {
      int s = edge_src[e];
      ushort4 v = *(const ushort4*)(&Xb[(size_t)s * 512 + lane * 4]);
      acc[0] += bf2f(v.x); acc[1] += bf2f(v.y);
      acc[2] += bf2f(v.z); acc[3] += bf2f(v.w);
    }
    ushort4 o;
    o.x = f2bf(acc[0]); o.y = f2bf(acc[1]); o.z = f2bf(acc[2]); o.w = f2bf(acc[3]);
    *(ushort4*)(&Xb[(size_t)i * 512 + 256 + lane * 4]) = o;
  } else {
    // prep_w: Wt[e][n][k] bf16 transpose-pack
    int pw = blockIdx.x - NAGG;
    int kt = pw & 15, nt = (pw >> 4) & 7, z = pw >> 7;
    int e = z & 7;
    const float* Ws = (z < 8) ? Ws0 : Ws1;
    const float* Wn = (z < 8) ? Wn0 : Wn1;
    ushort_t* Wt = (z < 8) ? Wt1 : Wt2;
    int tx = t & 31, ty = t >> 5;
    const float* src = (kt < 8) ? (Ws + e * 65536 + (kt * 32) * 256)
                                : (Wn + e * 65536 + ((kt - 8) * 32) * 256);
#pragma unroll
    for (int rr = 0; rr < 32; rr += 8) {
      int k = rr + ty;
      tile[k][tx] = src[k * 256 + nt * 32 + tx];
    }
    __syncthreads();
#pragma unroll
    for (int rr = 0; rr < 32; rr += 8) {
      int n = rr + ty;
      Wt[(size_t)e * 131072 + (nt * 32 + n) * 512 + kt * 32 + tx] = f2bf(tile[tx][n]);
    }
  }
}

// ------- router GEMM fp32 (argmax fidelity) + inline size features ----------
#define RBM 64
#define RBN 128
#define RBK 32
__global__ __launch_bounds__(256) void k_router(
    const float* __restrict__ H32, const float* __restrict__ Wr1,
    const float* __restrict__ br1, const int* __restrict__ batch,
    const int* __restrict__ node_cnt, const int* __restrict__ edge_cnt,
    float* __restrict__ R) {
  __shared__ float As[RBK][RBM + 1];   // pad 65: staging writes <=2-way (free)
  __shared__ float Bs[RBK][RBN + 4];
  int t = threadIdx.x;
  int row0 = blockIdx.x * RBM;
  int n0 = blockIdx.y * RBN;
  int tn = t & 31, tm = t >> 5;
  int arow = t >> 2, ak0 = (t & 3) * 8;
  int bcol = (t & 31) * 4, bk0 = (t >> 5) * 4;
  float acc[8][4] = {};
  for (int k0 = 0; k0 < 256; k0 += RBK) {
    int gr = row0 + arow;
#pragma unroll
    for (int h = 0; h < 2; h++) {
      float4 va = {0.f, 0.f, 0.f, 0.f};
      if (gr < NN) va = *(const float4*)(&H32[gr * 256 + k0 + ak0 + h * 4]);
      As[ak0 + h * 4 + 0][arow] = va.x;
      As[ak0 + h * 4 + 1][arow] = va.y;
      As[ak0 + h * 4 + 2][arow] = va.z;
      As[ak0 + h * 4 + 3][arow] = va.w;
    }
#pragma unroll
    for (int q = 0; q < 4; q++) {
      float4 vb = *(const float4*)(&Wr1[(k0 + bk0 + q) * 256 + n0 + bcol]);
      *(float4*)(&Bs[bk0 + q][bcol]) = vb;
    }
    __syncthreads();
#pragma unroll
    for (int k = 0; k < RBK; k++) {
      float a[8];
      float4 b4 = *(const float4*)(&Bs[k][tn * 4]);
      float b[4] = {b4.x, b4.y, b4.z, b4.w};
#pragma unroll
      for (int i = 0; i < 8; i++) a[i] = As[k][tm * 8 + i];
#pragma unroll
      for (int i = 0; i < 8; i++)
#pragma unroll
        for (int j = 0; j < 4; j++) acc[i][j] = fmaf(a[i], b[j], acc[i][j]);
    }
    __syncthreads();
  }
  float4 bb = *(const float4*)(&br1[n0 + tn * 4]);
  float4 w6 = *(const float4*)(&Wr1[65536 + n0 + tn * 4]);  // row 256
  float4 w7 = *(const float4*)(&Wr1[65792 + n0 + tn * 4]);  // row 257
#pragma unroll
  for (int i = 0; i < 8; i++) {
    int r = row0 + tm * 8 + i;
    if (r >= NN) break;
    int g = batch[r];
    float s0 = log1pf((float)node_cnt[g]);   // identical to old k_sizefeat
    float s1 = log1pf((float)edge_cnt[g]);
    float4 o;
    o.x = fmaxf(acc[i][0] + s0 * w6.x + s1 * w7.x + bb.x, 0.f);
    o.y = fmaxf(acc[i][1] + s0 * w6.y + s1 * w7.y + bb.y, 0.f);
    o.z = fmaxf(acc[i][2] + s0 * w6.z + s1 * w7.z + bb.z, 0.f);
    o.w = fmaxf(acc[i][3] + s0 * w6.w + s1 * w7.w + bb.w, 0.f);
    *(float4*)(&R[r * 256 + n0 + tn * 4]) = o;
  }
}

// ------ logits + argmax + expert histogram (grid-strided, 256 blocks) -------
__global__ __launch_bounds__(256) void k_logits(
    const float* __restrict__ R, const float* __restrict__ Wr2,
    const float* __restrict__ br2, int* __restrict__ idx, int* __restrict__ ecnt) {
  __shared__ int bins[NEXP];
  int t = threadIdx.x, wid = t >> 6, lane = t & 63;
  if (t < NEXP) bins[t] = 0;
  __syncthreads();
  for (int grp = blockIdx.x; grp < NAGG; grp += gridDim.x) {
    int i = grp * 4 + wid;
    if (i < NN) {
      float4 r4 = *(const float4*)(&R[i * 256 + lane * 4]);
      float rv[4] = {r4.x, r4.y, r4.z, r4.w};
      float acc[NEXP] = {};
#pragma unroll
      for (int kk = 0; kk < 4; kk++) {
        int k = lane * 4 + kk;
#pragma unroll
        for (int e = 0; e < NEXP; e++) acc[e] = fmaf(rv[kk], Wr2[k * 8 + e], acc[e]);
      }
#pragma unroll
      for (int d = 32; d > 0; d >>= 1)
#pragma unroll
        for (int e = 0; e < NEXP; e++) acc[e] += __shfl_xor(acc[e], d, 64);
      if (lane == 0) {
        float best = -1e30f; int bi = 0;
        for (int e = 0; e < NEXP; e++) {
          float v = acc[e] + br2[e];
          if (v > best) { best = v; bi = e; }   // strict >: first-wins = jnp.argmax
        }
        idx[i] = bi;
        atomicAdd(&bins[bi], 1);
      }
    }
  }
  __syncthreads();
  if (t < NEXP) atomicAdd(&ecnt[t], bins[t]);
}

// ---- block-aggregated bucket fill (boff computed locally from ecnt) --------
#define BF_BLOCKS 64
__global__ __launch_bounds__(256) void k_bucket_fill2(
    const int* __restrict__ idx, const int* __restrict__ ecnt,
    int* __restrict__ bcur, int* __restrict__ nlist) {
  __shared__ int lcnt[NEXP];
  __shared__ int lbase[NEXP];
  int t = threadIdx.x;
  int chunk = (NN + BF_BLOCKS - 1) / BF_BLOCKS;
  int lo = blockIdx.x * chunk;
  int hi = lo + chunk; if (hi > NN) hi = NN;
  if (t < NEXP) lcnt[t] = 0;
  __syncthreads();
  for (int i = lo + t; i < hi; i += 256) atomicAdd(&lcnt[idx[i]], 1);
  __syncthreads();
  if (t < NEXP) {
    int myboff = 0;
    for (int q = 0; q < t; q++) myboff += ecnt[q];
    lbase[t] = myboff + atomicAdd(&bcur[t], lcnt[t]);
  }
  __syncthreads();
  if (t < NEXP) lcnt[t] = 0;
  __syncthreads();
  for (int i = lo + t; i < hi; i += 256) {
    int e = idx[i];
    int p = atomicAdd(&lcnt[e], 1);
    nlist[lbase[e] + p] = i;
  }
}

// ======== fused expert step: layer1(e1) MFMA blocks + agg_z(e0) blocks ======
// blocks [0, nt1):      z_{e1} = relu(Xb @ Wt1_{e1}^T + b0) -> Zw, self->A2
// blocks [nt1, ...):    A2[i,256:512] = sum_{j in Nin(i)} Zr[j], i in bucket e0
__global__ __launch_bounds__(256) void k_l1agg(
    const ushort_t* __restrict__ Abf, const ushort_t* __restrict__ Wt,
    const float* __restrict__ b0, const int* __restrict__ idx, int e1,
    ushort_t* __restrict__ Zw, ushort_t* __restrict__ A2,
    const ushort_t* __restrict__ Zr, const int* __restrict__ offs,
    const int* __restrict__ edge_src, const int* __restrict__ nlist,
    const int* __restrict__ ecnt, int e0, int nt1) {
  __shared__ ushort_t As[128 * 32];
  __shared__ ushort_t Bs[128 * 32];
  __shared__ int sidx[128];
  int t = threadIdx.x;
  if ((int)blockIdx.x < nt1) {
    // ---------------- layer1 MFMA role ----------------
    int w = t >> 6, lane = t & 63;
    int m0 = (blockIdx.x >> 1) * 128;
    int n0 = (blockIdx.x & 1) * 128;
    int wm = w >> 1, wn = w & 1;
    const ushort_t* Wb = Wt + (size_t)e1 * 131072;
    if (t < 128) {
      int r = m0 + t;
      sidx[t] = (r < NN) ? idx[r] : -1;
    }
    f32x4 acc[4][4] = {};
    for (int kt = 0; kt < 16; kt++) {
      int k0 = kt * 32;
#pragma unroll
      for (int i = 0; i < 2; i++) {
        int c = w * 128 + i * 64 + lane;
        int r = c >> 2, kc = c & 3;
        int gr = m0 + r; if (gr >= NN) gr = NN - 1;
        gld16(Abf + (size_t)gr * 512 + k0 + kc * 8,
              (void*)&As[(w * 128 + i * 64) * 8]);
        gld16(Wb + (size_t)(n0 + r) * 512 + k0 + kc * 8,
              (void*)&Bs[(w * 128 + i * 64) * 8]);
      }
      __syncthreads();
      bf16x8 a[4], b[4];
#pragma unroll
      for (int i = 0; i < 4; i++) {
        int ra = wm * 64 + i * 16 + (lane & 15);
        a[i] = *(const bf16x8*)&As[ra * 32 + (lane >> 4) * 8];
        int nb = wn * 64 + i * 16 + (lane & 15);
        b[i] = *(const bf16x8*)&Bs[nb * 32 + (lane >> 4) * 8];
      }
#pragma unroll
      for (int i = 0; i < 4; i++)
#pragma unroll
        for (int j = 0; j < 4; j++)
          acc[i][j] = __builtin_amdgcn_mfma_f32_16x16x32_bf16(a[i], b[j], acc[i][j], 0, 0, 0);
      __syncthreads();
    }
    int q = lane >> 4, c15 = lane & 15;
#pragma unroll
    for (int i = 0; i < 4; i++) {
#pragma unroll
      for (int j = 0; j < 4; j++) {
        int col = n0 + wn * 64 + j * 16 + c15;
        float bias = b0[e1 * 256 + col];
#pragma unroll
        for (int v = 0; v < 4; v++) {
          int lrow = wm * 64 + i * 16 + q * 4 + v;
          int row = m0 + lrow;
          if (row < NN) {
            unsigned short zb = f2bf(fmaxf(acc[i][j][v] + bias, 0.f));
            Zw[(size_t)row * 256 + col] = zb;
            if (sidx[lrow] == e1) A2[(size_t)row * 512 + col] = zb;
          }
        }
      }
    }
  } else {
    // ---------------- agg_z role (expert e0) ----------------
    int ib = blockIdx.x - nt1;
    int wid = t >> 6, lane = t & 63;
    int b = ib * 4 + wid;
    int base = 0;
#pragma unroll
    for (int qq = 0; qq < NEXP; qq++) if (qq < e0) base += ecnt[qq];
    int cnt = ecnt[e0];
    if (b >= cnt) return;
    int i = nlist[base + b];
    int s0 = offs[i], s1 = offs[i + 1];
    float acc[4] = {0.f, 0.f, 0.f, 0.f};
    for (int k = s0; k < s1; k++) {
      int s = edge_src[k];
      ushort4 v = *(const ushort4*)(&Zr[(size_t)s * 256 + lane * 4]);
      acc[0] += bf2f(v.x); acc[1] += bf2f(v.y);
      acc[2] += bf2f(v.z); acc[3] += bf2f(v.w);
    }
    ushort4 o;
    o.x = f2bf(acc[0]); o.y = f2bf(acc[1]); o.z = f2bf(acc[2]); o.w = f2bf(acc[3]);
    *(ushort4*)(&A2[(size_t)i * 512 + 256 + lane * 4]) = o;
  }
}

// ------- fused layer2 MFMA over all buckets (prefixes computed locally) -----
__global__ __launch_bounds__(256) void k_layer2_mfma(
    const ushort_t* __restrict__ A2, const ushort_t* __restrict__ Wt,
    const float* __restrict__ b1, const int* __restrict__ nlist,
    const int* __restrict__ ecnt, float* __restrict__ outp) {
  __shared__ ushort_t As[128 * 32];
  __shared__ ushort_t Bs[128 * 32];
  __shared__ int rows[128];
  int t = threadIdx.x;
  int tx = blockIdx.x;
  int ts = 0, base = 0, e = -1, tile = 0, cnt = 0;
#pragma unroll
  for (int q = 0; q < NEXP; q++) {
    int c = ecnt[q];
    int nt = (c + 127) >> 7;
    if (e < 0 && tx < ts + nt) { e = q; tile = tx - ts; cnt = c; break; }
    ts += nt; base += c;
  }
  if (e < 0) return;
  int m0 = tile * 128;
  if (t < 128) rows[t] = (m0 + t < cnt) ? nlist[base + m0 + t] : -1;
  __syncthreads();
  int w = t >> 6, lane = t & 63;
  int n0 = blockIdx.y * 128;
  int wm = w >> 1, wn = w & 1;
  const ushort_t* Wb = Wt + (size_t)e * 131072;
  f32x4 acc[4][4] = {};
  for (int kt = 0; kt < 16; kt++) {
    int k0 = kt * 32;
#pragma unroll
    for (int i = 0; i < 2; i++) {
      int c = w * 128 + i * 64 + lane;
      int r = c >> 2, kc = c & 3;
      int nd = rows[r]; if (nd < 0) nd = 0;
      gld16(A2 + (size_t)nd * 512 + k0 + kc * 8,
            (void*)&As[(w * 128 + i * 64) * 8]);
      gld16(Wb + (size_t)(n0 + r) * 512 + k0 + kc * 8,
            (void*)&Bs[(w * 128 + i * 64) * 8]);
    }
    __syncthreads();
    bf16x8 a[4], b[4];
#pragma unroll
    for (int i = 0; i < 4; i++) {
      int ra = wm * 64 + i * 16 + (lane & 15);
      a[i] = *(const bf16x8*)&As[ra * 32 + (lane >> 4) * 8];
      int nb = wn * 64 + i * 16 + (lane & 15);
      b[i] = *(const bf16x8*)&Bs[nb * 32 + (lane >> 4) * 8];
    }
#pragma unroll
    for (int i = 0; i < 4; i++)
#pragma unroll
      for (int j = 0; j < 4; j++)
        acc[i][j] = __builtin_amdgcn_mfma_f32_16x16x32_bf16(a[i], b[j], acc[i][j], 0, 0, 0);
    __syncthreads();
  }
  int q = lane >> 4, c15 = lane & 15;
#pragma unroll
  for (int i = 0; i < 4; i++) {
#pragma unroll
    for (int j = 0; j < 4; j++) {
      int col = n0 + wn * 64 + j * 16 + c15;
      float bias = b1[e * 256 + col];
#pragma unroll
      for (int v = 0; v < 4; v++) {
        int lrow = wm * 64 + i * 16 + q * 4 + v;
        int node = rows[lrow];
        if (node >= 0) outp[(size_t)node * 256 + col] = acc[i][j][v] + bias;
      }
    }
  }
}

static inline char* wsalloc(char*& p, size_t bytes) {
  char* r = p;
  p += (bytes + 255) & ~(size_t)255;
  return r;
}

extern "C" void kernel_launch(void* const* d_in, const int* in_sizes, int n_in,
                              void* d_out, int out_size, void* d_ws, size_t ws_size,
                              hipStream_t stream) {
  const float* x     = (const float*)d_in[0];
  const int*   ei    = (const int*)d_in[1];
  const int*   batch = (const int*)d_in[2];
  const float* W_enc = (const float*)d_in[3];
  const float* b_enc = (const float*)d_in[4];
  const float* Wr1   = (const float*)d_in[5];
  const float* br1   = (const float*)d_in[6];
  const float* Wr2   = (const float*)d_in[7];
  const float* br2   = (const float*)d_in[8];
  const float* Ws0   = (const float*)d_in[9];
  const float* Wn0   = (const float*)d_in[10];
  const float* b0    = (const float*)d_in[11];
  const float* Ws1   = (const float*)d_in[12];
  const float* Wn1   = (const float*)d_in[13];
  const float* b1    = (const float*)d_in[14];
  float* outp = (float*)d_out;

  char* p = (char*)d_ws;
  float*    H32  = (float*)wsalloc(p, (size_t)NN * 256 * 4);     // fp32 h; dead after router
  ushort_t* Zb1  = (ushort_t*)H32;                               // alias: Zb odd buffer
  ushort_t* Xb   = (ushort_t*)wsalloc(p, (size_t)NN * 512 * 2);  // [h | A_h] bf16
  ushort_t* Zb0  = (ushort_t*)wsalloc(p, (size_t)NN * 256 * 2);  // Zb even buffer
  ushort_t* A2   = (ushort_t*)wsalloc(p, (size_t)NN * 512 * 2);  // [z_self | agg] bf16
  float*    R    = (float*)A2;                                   // alias: R dies before A2 born
  ushort_t* Wt1  = (ushort_t*)wsalloc(p, (size_t)NEXP * 256 * 512 * 2);
  ushort_t* Wt2  = (ushort_t*)wsalloc(p, (size_t)NEXP * 256 * 512 * 2);
  int* edge_src  = (int*)wsalloc(p, (size_t)NE * 4);
  int* offs      = (int*)wsalloc(p, (size_t)(NN + 1) * 4);
  int* cursor    = (int*)wsalloc(p, (size_t)NN * 4);
  int* deg       = (int*)wsalloc(p, (size_t)NN * 4);
  int* idxb      = (int*)wsalloc(p, (size_t)NN * 4);
  int* nlist     = (int*)wsalloc(p, (size_t)NN * 4);
  int* smallb    = (int*)wsalloc(p, 256 * 4);
  int* node_cnt = smallb;        // 64
  int* edge_cnt = smallb + 64;   // 64
  int* ecnt     = smallb + 128;  // 8
  int* bcur     = smallb + 136;  // 8

  ushort_t* Z[2] = {Zb0, Zb1};

  hipMemsetAsync(deg, 0, (size_t)NN * 4, stream);
  hipMemsetAsync(smallb, 0, 256 * 4, stream);

  k_encoder<<<NN, 256, 0, stream>>>(x, W_enc, b_enc, H32, Xb);
  k_counts<<<128, 256, 0, stream>>>(batch, ei, node_cnt, edge_cnt, deg);
  k_scan<<<1, 1024, 0, stream>>>(deg, offs, cursor);
  k_fill_csr<<<(NE + 255) / 256, 256, 0, stream>>>(ei, cursor, edge_src);
  k_aggh_prepw<<<NAGG + 2048, 256, 0, stream>>>(offs, edge_src, Xb,
                                                Ws0, Wn0, Ws1, Wn1, Wt1, Wt2);
  k_router<<<dim3((NN + RBM - 1) / RBM, 2), 256, 0, stream>>>(
      H32, Wr1, br1, batch, node_cnt, edge_cnt, R);
  k_logits<<<256, 256, 0, stream>>>(R, Wr2, br2, idxb, ecnt);
  k_bucket_fill2<<<BF_BLOCKS, 256, 0, stream>>>(idxb, ecnt, bcur, nlist);

  // e=0: layer1 only
  k_l1agg<<<NT1, 256, 0, stream>>>(Xb, Wt1, b0, idxb, 0, Z[0], A2,
                                   Z[0], offs, edge_src, nlist, ecnt, -1, NT1);
  // e=1..7: layer1(e) fused with agg_z(e-1)
  for (int e = 1; e < NEXP; e++) {
    k_l1agg<<<NT1 + NAGG, 256, 0, stream>>>(Xb, Wt1, b0, idxb, e, Z[e & 1], A2,
                                            Z[(e - 1) & 1], offs, edge_src,
                                            nlist, ecnt, e - 1, NT1);
  }
  // final agg_z(7)
  k_l1agg<<<NAGG, 256, 0, stream>>>(Xb, Wt1, b0, idxb, 0, Z[0], A2,
                                    Z[7 & 1], offs, edge_src, nlist, ecnt, 7, 0);
  k_layer2_mfma<<<dim3(MAXT2, 2), 256, 0, stream>>>(A2, Wt2, b1, nlist, ecnt, outp);
}

// Round 7
// 1031.060 us; speedup vs baseline: 1.0202x; 1.0202x over previous
//
#include <hip/hip_runtime.h>
#include <hip/hip_bf16.h>
#include <math.h>

#define NN 50000
#define NE 800000
#define NG 64
#define NEXP 8

typedef __attribute__((ext_vector_type(8))) short bf16x8;
typedef __attribute__((ext_vector_type(4))) float f32x4;
typedef unsigned short ushort_t;

#define NAGG 12500   // agg blocks: 50000 nodes / 4 waves per block
#define MAXT2 (391 + NEXP)

__device__ __forceinline__ unsigned short f2bf(float f) {
  union { float f; unsigned u; } x; x.f = f;
  unsigned r = x.u + 0x7fff + ((x.u >> 16) & 1);  // RNE
  return (unsigned short)(r >> 16);
}
__device__ __forceinline__ float bf2f(unsigned short u) {
  union { unsigned u; float f; } x; x.u = ((unsigned)u) << 16; return x.f;
}

__device__ __forceinline__ void gld16(const void* g, void* l) {
  __builtin_amdgcn_global_load_lds(
      (const __attribute__((address_space(1))) unsigned int*)g,
      (__attribute__((address_space(3))) unsigned int*)l, 16, 0, 0);
}

// -------- encoder: h = relu(x@W_enc+b); fp32 copy for router, bf16 for MFMA --
__global__ __launch_bounds__(256) void k_encoder(
    const float* __restrict__ x, const float* __restrict__ W,
    const float* __restrict__ b, float* __restrict__ H32,
    ushort_t* __restrict__ Xb) {
  int i = blockIdx.x, n = threadIdx.x;
  float acc = b[n];
#pragma unroll
  for (int k = 0; k < 6; k++) acc = fmaf(x[i * 6 + k], W[k * 256 + n], acc);
  acc = fmaxf(acc, 0.f);
  H32[i * 256 + n] = acc;
  Xb[(size_t)i * 512 + n] = f2bf(acc);
}

// ------ merged per-graph node+edge histograms + in-degree (one dispatch) ----
__global__ __launch_bounds__(256) void k_counts(
    const int* __restrict__ batch, const int* __restrict__ ei,
    int* __restrict__ node_cnt, int* __restrict__ edge_cnt,
    int* __restrict__ deg) {
  __shared__ int bn[NG], be[NG];
  int t = threadIdx.x;
  if (t < NG) { bn[t] = 0; be[t] = 0; }
  __syncthreads();
  for (int i = blockIdx.x * 256 + t; i < NN; i += gridDim.x * 256)
    atomicAdd(&bn[batch[i]], 1);
  for (int e = blockIdx.x * 256 + t; e < NE; e += gridDim.x * 256) {
    int s = ei[e];
    int d = ei[NE + e];
    atomicAdd(&be[batch[s]], 1);
    atomicAdd(&deg[d], 1);
  }
  __syncthreads();
  if (t < NG) {
    atomicAdd(&node_cnt[t], bn[t]);
    atomicAdd(&edge_cnt[t], be[t]);
  }
}

// ---------------- exclusive prefix scan of deg (single block) ----------------
__global__ __launch_bounds__(1024) void k_scan(
    const int* __restrict__ deg, int* __restrict__ offs, int* __restrict__ cursor) {
  __shared__ int wsums[16];
  int t = threadIdx.x, lane = t & 63, wid = t >> 6;
  int carry = 0;
  for (int base = 0; base < NN; base += 1024) {
    int i = base + t;
    int v = (i < NN) ? deg[i] : 0;
    int x = v;
#pragma unroll
    for (int d = 1; d < 64; d <<= 1) {
      int y = __shfl_up(x, d, 64);
      if (lane >= d) x += y;
    }
    if (lane == 63) wsums[wid] = x;
    __syncthreads();
    if (wid == 0) {
      int s = (lane < 16) ? wsums[lane] : 0;
#pragma unroll
      for (int d = 1; d < 16; d <<= 1) {
        int y = __shfl_up(s, d, 64);
        if (lane >= d) s += y;
      }
      if (lane < 16) wsums[lane] = s;
    }
    __syncthreads();
    int wpre = (wid > 0) ? wsums[wid - 1] : 0;
    int excl = carry + wpre + x - v;
    if (i < NN) { offs[i] = excl; cursor[i] = excl; }
    int btot = wsums[15];
    __syncthreads();
    carry += btot;
  }
  if (t == 0) offs[NN] = carry;
}

// ---------------- CSR fill: bucket edges by dst ----------------
__global__ __launch_bounds__(256) void k_fill_csr(
    const int* __restrict__ ei, int* __restrict__ cursor, int* __restrict__ edge_src) {
  int e = blockIdx.x * blockDim.x + threadIdx.x;
  if (e < NE) {
    int d = ei[NE + e];
    int pos = atomicAdd(&cursor[d], 1);
    edge_src[pos] = ei[e];
  }
}

// ---- fused: blocks [0,NAGG) agg_h; blocks [NAGG, NAGG+2048) prep_w ---------
__global__ __launch_bounds__(256) void k_aggh_prepw(
    const int* __restrict__ offs, const int* __restrict__ edge_src,
    ushort_t* __restrict__ Xb,
    const float* __restrict__ Ws0, const float* __restrict__ Wn0,
    const float* __restrict__ Ws1, const float* __restrict__ Wn1,
    ushort_t* __restrict__ Wt1, ushort_t* __restrict__ Wt2) {
  __shared__ float tile[32][33];
  int t = threadIdx.x;
  if ((int)blockIdx.x < NAGG) {
    int wid = t >> 6, lane = t & 63;
    int i = blockIdx.x * 4 + wid;
    if (i >= NN) return;
    int e0 = offs[i], e1 = offs[i + 1];
    float acc[4] = {0.f, 0.f, 0.f, 0.f};
    for (int e = e0; e < e1; e++) {
      int s = edge_src[e];
      ushort4 v = *(const ushort4*)(&Xb[(size_t)s * 512 + lane * 4]);
      acc[0] += bf2f(v.x); acc[1] += bf2f(v.y);
      acc[2] += bf2f(v.z); acc[3] += bf2f(v.w);
    }
    ushort4 o;
    o.x = f2bf(acc[0]); o.y = f2bf(acc[1]); o.z = f2bf(acc[2]); o.w = f2bf(acc[3]);
    *(ushort4*)(&Xb[(size_t)i * 512 + 256 + lane * 4]) = o;
  } else {
    int pw = blockIdx.x - NAGG;
    int kt = pw & 15, nt = (pw >> 4) & 7, z = pw >> 7;
    int e = z & 7;
    const float* Ws = (z < 8) ? Ws0 : Ws1;
    const float* Wn = (z < 8) ? Wn0 : Wn1;
    ushort_t* Wt = (z < 8) ? Wt1 : Wt2;
    int tx = t & 31, ty = t >> 5;
    const float* src = (kt < 8) ? (Ws + e * 65536 + (kt * 32) * 256)
                                : (Wn + e * 65536 + ((kt - 8) * 32) * 256);
#pragma unroll
    for (int rr = 0; rr < 32; rr += 8) {
      int k = rr + ty;
      tile[k][tx] = src[k * 256 + nt * 32 + tx];
    }
    __syncthreads();
#pragma unroll
    for (int rr = 0; rr < 32; rr += 8) {
      int n = rr + ty;
      Wt[(size_t)e * 131072 + (nt * 32 + n) * 512 + kt * 32 + tx] = f2bf(tile[tx][n]);
    }
  }
}

// --- router GEMM fp32 v3: BM=64, BN=256 single pass, split-halves b128 reads -
#define RBM 64
#define RBK 32
__global__ __launch_bounds__(256) void k_router(
    const float* __restrict__ H32, const float* __restrict__ Wr1,
    const float* __restrict__ br1, const int* __restrict__ batch,
    const int* __restrict__ node_cnt, const int* __restrict__ edge_cnt,
    float* __restrict__ R) {
  __shared__ float As[RBK][RBM + 1];    // pad 65
  __shared__ float Bs[RBK][256 + 4];
  int t = threadIdx.x;
  int row0 = blockIdx.x * RBM;
  int tn = t & 31, tm = t >> 5;
  int arow = t >> 2, ak0 = (t & 3) * 8;
  int bcol = (t & 63) * 4, bkr = t >> 6;   // 4 k-rows per pass, 8 passes
  float acc[8][8] = {};
  for (int k0 = 0; k0 < 256; k0 += RBK) {
    int gr = row0 + arow;
#pragma unroll
    for (int h = 0; h < 2; h++) {
      float4 va = {0.f, 0.f, 0.f, 0.f};
      if (gr < NN) va = *(const float4*)(&H32[gr * 256 + k0 + ak0 + h * 4]);
      As[ak0 + h * 4 + 0][arow] = va.x;
      As[ak0 + h * 4 + 1][arow] = va.y;
      As[ak0 + h * 4 + 2][arow] = va.z;
      As[ak0 + h * 4 + 3][arow] = va.w;
    }
#pragma unroll
    for (int q = 0; q < 8; q++) {
      float4 vb = *(const float4*)(&Wr1[(k0 + q * 4 + bkr) * 256 + bcol]);
      *(float4*)(&Bs[q * 4 + bkr][bcol]) = vb;
    }
    __syncthreads();
#pragma unroll
    for (int k = 0; k < RBK; k++) {
      float a[8];
      float4 bl = *(const float4*)(&Bs[k][tn * 4]);        // 16B stride: minimal banks
      float4 bh = *(const float4*)(&Bs[k][128 + tn * 4]);  // second half, same pattern
      float b[8] = {bl.x, bl.y, bl.z, bl.w, bh.x, bh.y, bh.z, bh.w};
#pragma unroll
      for (int i = 0; i < 8; i++) a[i] = As[k][tm * 8 + i];  // broadcast
#pragma unroll
      for (int i = 0; i < 8; i++)
#pragma unroll
        for (int j = 0; j < 8; j++) acc[i][j] = fmaf(a[i], b[j], acc[i][j]);
    }
    __syncthreads();
  }
  float4 bbl = *(const float4*)(&br1[tn * 4]);
  float4 bbh = *(const float4*)(&br1[128 + tn * 4]);
  float4 w6l = *(const float4*)(&Wr1[65536 + tn * 4]);        // row 256
  float4 w6h = *(const float4*)(&Wr1[65536 + 128 + tn * 4]);
  float4 w7l = *(const float4*)(&Wr1[65792 + tn * 4]);        // row 257
  float4 w7h = *(const float4*)(&Wr1[65792 + 128 + tn * 4]);
#pragma unroll
  for (int i = 0; i < 8; i++) {
    int r = row0 + tm * 8 + i;
    if (r >= NN) break;
    int g = batch[r];
    float s0 = log1pf((float)node_cnt[g]);
    float s1 = log1pf((float)edge_cnt[g]);
    float4 ol, oh;
    ol.x = fmaxf(acc[i][0] + s0 * w6l.x + s1 * w7l.x + bbl.x, 0.f);
    ol.y = fmaxf(acc[i][1] + s0 * w6l.y + s1 * w7l.y + bbl.y, 0.f);
    ol.z = fmaxf(acc[i][2] + s0 * w6l.z + s1 * w7l.z + bbl.z, 0.f);
    ol.w = fmaxf(acc[i][3] + s0 * w6l.w + s1 * w7l.w + bbl.w, 0.f);
    oh.x = fmaxf(acc[i][4] + s0 * w6h.x + s1 * w7h.x + bbh.x, 0.f);
    oh.y = fmaxf(acc[i][5] + s0 * w6h.y + s1 * w7h.y + bbh.y, 0.f);
    oh.z = fmaxf(acc[i][6] + s0 * w6h.z + s1 * w7h.z + bbh.z, 0.f);
    oh.w = fmaxf(acc[i][7] + s0 * w6h.w + s1 * w7h.w + bbh.w, 0.f);
    *(float4*)(&R[r * 256 + tn * 4]) = ol;
    *(float4*)(&R[r * 256 + 128 + tn * 4]) = oh;
  }
}

// ------ logits + argmax + expert histogram (grid-strided, 256 blocks) -------
__global__ __launch_bounds__(256) void k_logits(
    const float* __restrict__ R, const float* __restrict__ Wr2,
    const float* __restrict__ br2, int* __restrict__ idx, int* __restrict__ ecnt) {
  __shared__ int bins[NEXP];
  int t = threadIdx.x, wid = t >> 6, lane = t & 63;
  if (t < NEXP) bins[t] = 0;
  __syncthreads();
  for (int grp = blockIdx.x; grp < NAGG; grp += gridDim.x) {
    int i = grp * 4 + wid;
    if (i < NN) {
      float4 r4 = *(const float4*)(&R[i * 256 + lane * 4]);
      float rv[4] = {r4.x, r4.y, r4.z, r4.w};
      float acc[NEXP] = {};
#pragma unroll
      for (int kk = 0; kk < 4; kk++) {
        int k = lane * 4 + kk;
#pragma unroll
        for (int e = 0; e < NEXP; e++) acc[e] = fmaf(rv[kk], Wr2[k * 8 + e], acc[e]);
      }
#pragma unroll
      for (int d = 32; d > 0; d >>= 1)
#pragma unroll
        for (int e = 0; e < NEXP; e++) acc[e] += __shfl_xor(acc[e], d, 64);
      if (lane == 0) {
        float best = -1e30f; int bi = 0;
        for (int e = 0; e < NEXP; e++) {
          float v = acc[e] + br2[e];
          if (v > best) { best = v; bi = e; }   // strict >: first-wins = jnp.argmax
        }
        idx[i] = bi;
        atomicAdd(&bins[bi], 1);
      }
    }
  }
  __syncthreads();
  if (t < NEXP) atomicAdd(&ecnt[t], bins[t]);
}

// ---- block-aggregated bucket fill (boff computed locally from ecnt) --------
#define BF_BLOCKS 64
__global__ __launch_bounds__(256) void k_bucket_fill2(
    const int* __restrict__ idx, const int* __restrict__ ecnt,
    int* __restrict__ bcur, int* __restrict__ nlist) {
  __shared__ int lcnt[NEXP];
  __shared__ int lbase[NEXP];
  int t = threadIdx.x;
  int chunk = (NN + BF_BLOCKS - 1) / BF_BLOCKS;
  int lo = blockIdx.x * chunk;
  int hi = lo + chunk; if (hi > NN) hi = NN;
  if (t < NEXP) lcnt[t] = 0;
  __syncthreads();
  for (int i = lo + t; i < hi; i += 256) atomicAdd(&lcnt[idx[i]], 1);
  __syncthreads();
  if (t < NEXP) {
    int myboff = 0;
    for (int q = 0; q < t; q++) myboff += ecnt[q];
    lbase[t] = myboff + atomicAdd(&bcur[t], lcnt[t]);
  }
  __syncthreads();
  if (t < NEXP) lcnt[t] = 0;
  __syncthreads();
  for (int i = lo + t; i < hi; i += 256) {
    int e = idx[i];
    int p = atomicAdd(&lcnt[e], 1);
    nlist[lbase[e] + p] = i;
  }
}

// ------- layer1 bf16 MFMA: z_e = relu(Xb @ Wt1_e^T + b0_e) -> Zw (bf16) -----
// Also scatters self rows (idx[row]==e) into A2[:, 0:256].
__global__ __launch_bounds__(256) void k_layer1_mfma(
    const ushort_t* __restrict__ Abf, const ushort_t* __restrict__ Wt,
    const float* __restrict__ b0, const int* __restrict__ idx, int e,
    ushort_t* __restrict__ Zw, ushort_t* __restrict__ A2) {
  __shared__ ushort_t As[128 * 32];
  __shared__ ushort_t Bs[128 * 32];
  __shared__ int sidx[128];
  int t = threadIdx.x;
  int w = t >> 6, lane = t & 63;
  int m0 = blockIdx.x * 128;
  int n0 = blockIdx.y * 128;
  int wm = w >> 1, wn = w & 1;
  const ushort_t* Wb = Wt + (size_t)e * 131072;
  if (t < 128) {
    int r = m0 + t;
    sidx[t] = (r < NN) ? idx[r] : -1;
  }
  f32x4 acc[4][4] = {};
  for (int kt = 0; kt < 16; kt++) {
    int k0 = kt * 32;
#pragma unroll
    for (int i = 0; i < 2; i++) {
      int c = w * 128 + i * 64 + lane;
      int r = c >> 2, kc = c & 3;
      int gr = m0 + r; if (gr >= NN) gr = NN - 1;
      gld16(Abf + (size_t)gr * 512 + k0 + kc * 8,
            (void*)&As[(w * 128 + i * 64) * 8]);
      gld16(Wb + (size_t)(n0 + r) * 512 + k0 + kc * 8,
            (void*)&Bs[(w * 128 + i * 64) * 8]);
    }
    __syncthreads();
    bf16x8 a[4], b[4];
#pragma unroll
    for (int i = 0; i < 4; i++) {
      int ra = wm * 64 + i * 16 + (lane & 15);
      a[i] = *(const bf16x8*)&As[ra * 32 + (lane >> 4) * 8];
      int nb = wn * 64 + i * 16 + (lane & 15);
      b[i] = *(const bf16x8*)&Bs[nb * 32 + (lane >> 4) * 8];
    }
#pragma unroll
    for (int i = 0; i < 4; i++)
#pragma unroll
      for (int j = 0; j < 4; j++)
        acc[i][j] = __builtin_amdgcn_mfma_f32_16x16x32_bf16(a[i], b[j], acc[i][j], 0, 0, 0);
    __syncthreads();
  }
  int q = lane >> 4, c15 = lane & 15;
#pragma unroll
  for (int i = 0; i < 4; i++) {
#pragma unroll
    for (int j = 0; j < 4; j++) {
      int col = n0 + wn * 64 + j * 16 + c15;
      float bias = b0[e * 256 + col];
#pragma unroll
      for (int v = 0; v < 4; v++) {
        int lrow = wm * 64 + i * 16 + q * 4 + v;
        int row = m0 + lrow;
        if (row < NN) {
          unsigned short zb = f2bf(fmaxf(acc[i][j][v] + bias, 0.f));
          Zw[(size_t)row * 256 + col] = zb;
          if (sidx[lrow] == e) A2[(size_t)row * 512 + col] = zb;
        }
      }
    }
  }
}

// ---- agg_z bucket e: A2[i, 256:512] = bf16(sum_{j in Nin(i)} Zr[j]) --------
__global__ __launch_bounds__(256) void k_agg_z(
    const ushort_t* __restrict__ Zr, const int* __restrict__ offs,
    const int* __restrict__ edge_src, const int* __restrict__ nlist,
    const int* __restrict__ ecnt, int e0, ushort_t* __restrict__ A2) {
  int t = threadIdx.x;
  int wid = t >> 6, lane = t & 63;
  int b = blockIdx.x * 4 + wid;
  int base = 0;
#pragma unroll
  for (int qq = 0; qq < NEXP; qq++) if (qq < e0) base += ecnt[qq];
  int cnt = ecnt[e0];
  if (b >= cnt) return;
  int i = nlist[base + b];
  int s0 = offs[i], s1 = offs[i + 1];
  float acc[4] = {0.f, 0.f, 0.f, 0.f};
  for (int k = s0; k < s1; k++) {
    int s = edge_src[k];
    ushort4 v = *(const ushort4*)(&Zr[(size_t)s * 256 + lane * 4]);
    acc[0] += bf2f(v.x); acc[1] += bf2f(v.y);
    acc[2] += bf2f(v.z); acc[3] += bf2f(v.w);
  }
  ushort4 o;
  o.x = f2bf(acc[0]); o.y = f2bf(acc[1]); o.z = f2bf(acc[2]); o.w = f2bf(acc[3]);
  *(ushort4*)(&A2[(size_t)i * 512 + 256 + lane * 4]) = o;
}

// ------- fused layer2 MFMA over all buckets (prefixes computed locally) -----
__global__ __launch_bounds__(256) void k_layer2_mfma(
    const ushort_t* __restrict__ A2, const ushort_t* __restrict__ Wt,
    const float* __restrict__ b1, const int* __restrict__ nlist,
    const int* __restrict__ ecnt, float* __restrict__ outp) {
  __shared__ ushort_t As[128 * 32];
  __shared__ ushort_t Bs[128 * 32];
  __shared__ int rows[128];
  int t = threadIdx.x;
  int tx = blockIdx.x;
  int ts = 0, base = 0, e = -1, tile = 0, cnt = 0;
#pragma unroll
  for (int q = 0; q < NEXP; q++) {
    int c = ecnt[q];
    int nt = (c + 127) >> 7;
    if (e < 0 && tx < ts + nt) { e = q; tile = tx - ts; cnt = c; break; }
    ts += nt; base += c;
  }
  if (e < 0) return;
  int m0 = tile * 128;
  if (t < 128) rows[t] = (m0 + t < cnt) ? nlist[base + m0 + t] : -1;
  __syncthreads();
  int w = t >> 6, lane = t & 63;
  int n0 = blockIdx.y * 128;
  int wm = w >> 1, wn = w & 1;
  const ushort_t* Wb = Wt + (size_t)e * 131072;
  f32x4 acc[4][4] = {};
  for (int kt = 0; kt < 16; kt++) {
    int k0 = kt * 32;
#pragma unroll
    for (int i = 0; i < 2; i++) {
      int c = w * 128 + i * 64 + lane;
      int r = c >> 2, kc = c & 3;
      int nd = rows[r]; if (nd < 0) nd = 0;
      gld16(A2 + (size_t)nd * 512 + k0 + kc * 8,
            (void*)&As[(w * 128 + i * 64) * 8]);
      gld16(Wb + (size_t)(n0 + r) * 512 + k0 + kc * 8,
            (void*)&Bs[(w * 128 + i * 64) * 8]);
    }
    __syncthreads();
    bf16x8 a[4], b[4];
#pragma unroll
    for (int i = 0; i < 4; i++) {
      int ra = wm * 64 + i * 16 + (lane & 15);
      a[i] = *(const bf16x8*)&As[ra * 32 + (lane >> 4) * 8];
      int nb = wn * 64 + i * 16 + (lane & 15);
      b[i] = *(const bf16x8*)&Bs[nb * 32 + (lane >> 4) * 8];
    }
#pragma unroll
    for (int i = 0; i < 4; i++)
#pragma unroll
      for (int j = 0; j < 4; j++)
        acc[i][j] = __builtin_amdgcn_mfma_f32_16x16x32_bf16(a[i], b[j], acc[i][j], 0, 0, 0);
    __syncthreads();
  }
  int q = lane >> 4, c15 = lane & 15;
#pragma unroll
  for (int i = 0; i < 4; i++) {
#pragma unroll
    for (int j = 0; j < 4; j++) {
      int col = n0 + wn * 64 + j * 16 + c15;
      float bias = b1[e * 256 + col];
#pragma unroll
      for (int v = 0; v < 4; v++) {
        int lrow = wm * 64 + i * 16 + q * 4 + v;
        int node = rows[lrow];
        if (node >= 0) outp[(size_t)node * 256 + col] = acc[i][j][v] + bias;
      }
    }
  }
}

static inline char* wsalloc(char*& p, size_t bytes) {
  char* r = p;
  p += (bytes + 255) & ~(size_t)255;
  return r;
}

extern "C" void kernel_launch(void* const* d_in, const int* in_sizes, int n_in,
                              void* d_out, int out_size, void* d_ws, size_t ws_size,
                              hipStream_t stream) {
  const float* x     = (const float*)d_in[0];
  const int*   ei    = (const int*)d_in[1];
  const int*   batch = (const int*)d_in[2];
  const float* W_enc = (const float*)d_in[3];
  const float* b_enc = (const float*)d_in[4];
  const float* Wr1   = (const float*)d_in[5];
  const float* br1   = (const float*)d_in[6];
  const float* Wr2   = (const float*)d_in[7];
  const float* br2   = (const float*)d_in[8];
  const float* Ws0   = (const float*)d_in[9];
  const float* Wn0   = (const float*)d_in[10];
  const float* b0    = (const float*)d_in[11];
  const float* Ws1   = (const float*)d_in[12];
  const float* Wn1   = (const float*)d_in[13];
  const float* b1    = (const float*)d_in[14];
  float* outp = (float*)d_out;

  char* p = (char*)d_ws;
  float*    H32  = (float*)wsalloc(p, (size_t)NN * 256 * 4);     // fp32 h; dead after router
  ushort_t* Zb1  = (ushort_t*)H32;                               // alias: Zb odd buffer
  ushort_t* Xb   = (ushort_t*)wsalloc(p, (size_t)NN * 512 * 2);  // [h | A_h] bf16
  ushort_t* Zb0  = (ushort_t*)wsalloc(p, (size_t)NN * 256 * 2);  // Zb even buffer
  ushort_t* A2   = (ushort_t*)wsalloc(p, (size_t)NN * 512 * 2);  // [z_self | agg] bf16
  float*    R    = (float*)A2;                                   // alias: R dies before A2 born
  ushort_t* Wt1  = (ushort_t*)wsalloc(p, (size_t)NEXP * 256 * 512 * 2);
  ushort_t* Wt2  = (ushort_t*)wsalloc(p, (size_t)NEXP * 256 * 512 * 2);
  int* edge_src  = (int*)wsalloc(p, (size_t)NE * 4);
  int* offs      = (int*)wsalloc(p, (size_t)(NN + 1) * 4);
  int* cursor    = (int*)wsalloc(p, (size_t)NN * 4);
  int* deg       = (int*)wsalloc(p, (size_t)NN * 4);
  int* idxb      = (int*)wsalloc(p, (size_t)NN * 4);
  int* nlist     = (int*)wsalloc(p, (size_t)NN * 4);
  int* smallb    = (int*)wsalloc(p, 256 * 4);
  int* node_cnt = smallb;        // 64
  int* edge_cnt = smallb + 64;   // 64
  int* ecnt     = smallb + 128;  // 8
  int* bcur     = smallb + 136;  // 8

  ushort_t* Z[2] = {Zb0, Zb1};

  hipMemsetAsync(deg, 0, (size_t)NN * 4, stream);
  hipMemsetAsync(smallb, 0, 256 * 4, stream);

  k_encoder<<<NN, 256, 0, stream>>>(x, W_enc, b_enc, H32, Xb);
  k_counts<<<128, 256, 0, stream>>>(batch, ei, node_cnt, edge_cnt, deg);
  k_scan<<<1, 1024, 0, stream>>>(deg, offs, cursor);
  k_fill_csr<<<(NE + 255) / 256, 256, 0, stream>>>(ei, cursor, edge_src);
  k_aggh_prepw<<<NAGG + 2048, 256, 0, stream>>>(offs, edge_src, Xb,
                                                Ws0, Wn0, Ws1, Wn1, Wt1, Wt2);
  k_router<<<(NN + RBM - 1) / RBM, 256, 0, stream>>>(
      H32, Wr1, br1, batch, node_cnt, edge_cnt, R);
  k_logits<<<256, 256, 0, stream>>>(R, Wr2, br2, idxb, ecnt);
  k_bucket_fill2<<<BF_BLOCKS, 256, 0, stream>>>(idxb, ecnt, bcur, nlist);
  for (int e = 0; e < NEXP; e++) {
    k_layer1_mfma<<<dim3((NN + 127) / 128, 2), 256, 0, stream>>>(
        Xb, Wt1, b0, idxb, e, Z[e & 1], A2);
    k_agg_z<<<NAGG, 256, 0, stream>>>(Z[e & 1], offs, edge_src, nlist, ecnt, e, A2);
  }
  k_layer2_mfma<<<dim3(MAXT2, 2), 256, 0, stream>>>(A2, Wt2, b1, nlist, ecnt, outp);
}